// Round 9
// baseline (232.258 us; speedup 1.0000x reference)
//
#include <hip/hip_runtime.h>
#include <stdint.h>

typedef short short8 __attribute__((ext_vector_type(8)));
typedef float f32x4 __attribute__((ext_vector_type(4)));

#define AS1 __attribute__((address_space(1)))
#define AS3 __attribute__((address_space(3)))

__device__ __forceinline__ void gl_lds16(const void* g, void* l) {
  __builtin_amdgcn_global_load_lds((const AS1 unsigned int*)g,
                                   (AS3 unsigned int*)l, 16, 0, 0);
}

__device__ __forceinline__ unsigned short f2bf(float f) {
  union { float f; unsigned int u; } v; v.f = f;
  return (unsigned short)((v.u + (((v.u >> 16) & 1u) + 0x7fffu)) >> 16);
}

__device__ __forceinline__ void sink8(short8 v) { asm volatile("" :: "v"(v)); }
__device__ __forceinline__ void sinkf(f32x4 v) { asm volatile("" :: "v"(v)); }

// ---------------------------------------------------------------------------
// Pre-pass 1: x [16][256][64][64] fp32 NCHW -> x_t [16][64][64][256] bf16 NHWC
// ---------------------------------------------------------------------------
__global__ __launch_bounds__(256) void xpose_kernel(const float* __restrict__ x,
                                                    unsigned short* __restrict__ xt) {
  __shared__ float tile[64][68];
  const int bid = blockIdx.x;
  const int cchunk = bid & 3;
  const int y = (bid >> 2) & 63;
  const int b = bid >> 8;
  const int t = threadIdx.x;
  const int ci0 = cchunk * 64;

  const int cc = t >> 2;
  const int xo = (t & 3) * 16;
  const float* src = x + (((size_t)(b * 256 + ci0 + cc) * 64 + y) * 64 + xo);
  float4 v0 = ((const float4*)src)[0];
  float4 v1 = ((const float4*)src)[1];
  float4 v2 = ((const float4*)src)[2];
  float4 v3 = ((const float4*)src)[3];
  *(float4*)&tile[cc][xo + 0]  = v0;
  *(float4*)&tile[cc][xo + 4]  = v1;
  *(float4*)&tile[cc][xo + 8]  = v2;
  *(float4*)&tile[cc][xo + 12] = v3;
  __syncthreads();

  const int xpos = t >> 2;
  const int ccg = (t & 3) * 16;
  unsigned int pk[8];
#pragma unroll
  for (int e = 0; e < 8; ++e) {
    unsigned int lo = f2bf(tile[ccg + 2 * e][xpos]);
    unsigned int hi = f2bf(tile[ccg + 2 * e + 1][xpos]);
    pk[e] = lo | (hi << 16);
  }
  unsigned short* dst = xt + ((size_t)(b * 4096 + y * 64 + xpos) * 256 + ci0 + ccg);
  uint4 w0; w0.x = pk[0]; w0.y = pk[1]; w0.z = pk[2]; w0.w = pk[3];
  uint4 w1; w1.x = pk[4]; w1.y = pk[5]; w1.z = pk[6]; w1.w = pk[7];
  ((uint4*)dst)[0] = w0;
  ((uint4*)dst)[1] = w1;
}

// ---------------------------------------------------------------------------
// Pre-pass 2: w [256co][256ci][3][3] fp32 -> w_r [9 tap][256co][256ci] bf16
// ---------------------------------------------------------------------------
__global__ __launch_bounds__(256) void wpack_kernel(const float* __restrict__ w,
                                                    unsigned short* __restrict__ wrp) {
  const int idx = blockIdx.x * 256 + threadIdx.x;
  const int ci = idx & 255;
  const int co = (idx >> 8) & 255;
  const int p = idx >> 16;
  wrp[idx] = f2bf(w[(size_t)(co * 256 + ci) * 9 + p]);
}

// ---------------------------------------------------------------------------
// Ablation-instrumented 8-phase implicit-GEMM conv (m233-style decomposition).
// V=0 full (writes out) | V=1 no ds_read | V=2 no MFMA | V=3 no staging.
// ---------------------------------------------------------------------------
template <int V>
__global__ __launch_bounds__(512, 2) void conv_8ph(
    const unsigned short* __restrict__ xt,
    const unsigned short* __restrict__ wrp,
    const float* __restrict__ bias,
    float* __restrict__ out) {
  __shared__ unsigned short lds[2][32768];

  const int tid = threadIdx.x;
  const int lane = tid & 63;
  const int wv = tid >> 6;
  const int wm = wv >> 2;
  const int wn = wv & 3;
  const int bid = blockIdx.x;
  const int tile = (bid & 7) * 32 + (bid >> 3);
  const int b = tile >> 4;
  const int oh0 = (tile & 15) * 4;

  const int crow = tid >> 3;
  const int cslot = tid & 7;
  const int sw = cslot ^ (crow & 7);
  const unsigned short* gAbase = wrp + (size_t)crow * 256 + sw * 8;
  const unsigned short* gBbase[4];
#pragma unroll
  for (int cb = 0; cb < 4; ++cb) {
    const int y = min(oh0 + cb, 61);
    const int x = min(crow, 61);
    gBbase[cb] = xt + ((size_t)(b * 64 + y) * 64 + x) * 256 + sw * 8;
  }
  const unsigned dst_rc = crow * 64 + cslot * 8;

  const int l15 = lane & 15;
  int s8v[2];
  s8v[0] = (((lane >> 4)) ^ (lane & 7)) * 8;
  s8v[1] = (((lane >> 4) + 4) ^ (lane & 7)) * 8;
  int arow[8], brow[4];
#pragma unroll
  for (int a = 0; a < 8; ++a)
    arow[a] = (wm * 128 + (a >> 2) * 64 + (a & 3) * 16 + l15) * 64;
#pragma unroll
  for (int n = 0; n < 4; ++n)
    brow[n] = 16384 + (wn * 64 + n * 16 + l15) * 64;

  auto stageA = [&](int kt2, int c, unsigned short* bufp) {
    const int tap = kt2 >> 2, ci0 = (kt2 & 3) * 64;
    gl_lds16(gAbase + tap * 65536 + c * 16384 + ci0, bufp + c * 4096 + dst_rc);
  };
  auto stageB = [&](int kt2, int cb, unsigned short* bufp) {
    const int tap = kt2 >> 2, ci0 = (kt2 & 3) * 64;
    const int kh = (tap * 11) >> 5, kw = tap - kh * 3;
    gl_lds16(gBbase[cb] + (kh * 64 + kw) * 256 + ci0, bufp + (4 + cb) * 4096 + dst_rc);
  };

  f32x4 acc[8][4] = {};
  unsigned short* buf0 = &lds[0][0];
  unsigned short* buf1 = &lds[1][0];

  if constexpr (V != 3) {
    stageA(0, 0, buf0); stageA(0, 2, buf0); stageA(0, 1, buf0); stageA(0, 3, buf0);
    stageB(0, 2, buf0); stageB(0, 3, buf0); stageB(0, 0, buf0); stageB(0, 1, buf0);
    stageB(1, 0, buf1); stageB(1, 1, buf1);
    asm volatile("s_waitcnt vmcnt(2)" ::: "memory");
    __builtin_amdgcn_s_barrier();
  } else {
    // V3: fill both buffers once; no staging in the loop.
#pragma unroll
    for (int c = 0; c < 4; ++c) { stageA(0, c, buf0); stageB(0, c, buf0); }
#pragma unroll
    for (int c = 0; c < 4; ++c) { stageA(1, c, buf1); stageB(1, c, buf1); }
    asm volatile("s_waitcnt vmcnt(0)" ::: "memory");
    __builtin_amdgcn_s_barrier();
  }

  short8 a0[4], a1[4], bb[4];
  if constexpr (V == 1) {
    // load fragments once; loop does no ds_reads
#pragma unroll
    for (int q = 0; q < 4; ++q) a0[q] = *(const short8*)(buf0 + arow[q] + s8v[0]);
#pragma unroll
    for (int q = 0; q < 4; ++q) a1[q] = *(const short8*)(buf0 + arow[4 + q] + s8v[0]);
#pragma unroll
    for (int n = 0; n < 4; ++n) bb[n] = *(const short8*)(buf0 + brow[n] + s8v[0]);
    asm volatile("s_waitcnt lgkmcnt(0)" ::: "memory");
  }

  for (int kt = 0; kt < 36; ++kt) {
    unsigned short* buf = (kt & 1) ? buf1 : buf0;
    unsigned short* nbuf = (kt & 1) ? buf0 : buf1;

    // ---- p0 ----
    if constexpr (V != 1) {
#pragma unroll
      for (int q = 0; q < 4; ++q) a0[q] = *(const short8*)(buf + arow[q] + s8v[0]);
#pragma unroll
      for (int n = 0; n < 4; ++n) bb[n] = *(const short8*)(buf + brow[n] + s8v[0]);
    }
    if constexpr (V != 3) { if (kt < 35) { stageA(kt + 1, 0, nbuf); stageA(kt + 1, 2, nbuf); } }
    __builtin_amdgcn_s_barrier();
    __builtin_amdgcn_s_setprio(1);
    if constexpr (V != 2) {
#pragma unroll
      for (int q = 0; q < 4; ++q)
#pragma unroll
        for (int n = 0; n < 4; ++n)
          acc[q][n] = __builtin_amdgcn_mfma_f32_16x16x32_bf16(a0[q], bb[n], acc[q][n], 0, 0, 0);
    } else {
#pragma unroll
      for (int q = 0; q < 4; ++q) sink8(a0[q]);
#pragma unroll
      for (int n = 0; n < 4; ++n) sink8(bb[n]);
    }
    __builtin_amdgcn_s_setprio(0);
    asm volatile("s_waitcnt lgkmcnt(0)" ::: "memory");
    __builtin_amdgcn_s_barrier();

    // ---- p1 ----
    if constexpr (V != 1) {
#pragma unroll
      for (int q = 0; q < 4; ++q) a1[q] = *(const short8*)(buf + arow[4 + q] + s8v[0]);
    }
    if constexpr (V != 3) { if (kt < 35) { stageA(kt + 1, 1, nbuf); stageA(kt + 1, 3, nbuf); } }
    __builtin_amdgcn_s_barrier();
    __builtin_amdgcn_s_setprio(1);
    if constexpr (V != 2) {
#pragma unroll
      for (int q = 0; q < 4; ++q)
#pragma unroll
        for (int n = 0; n < 4; ++n)
          acc[4 + q][n] = __builtin_amdgcn_mfma_f32_16x16x32_bf16(a1[q], bb[n], acc[4 + q][n], 0, 0, 0);
    } else {
#pragma unroll
      for (int q = 0; q < 4; ++q) sink8(a1[q]);
    }
    __builtin_amdgcn_s_setprio(0);
    asm volatile("s_waitcnt lgkmcnt(0)" ::: "memory");
    __builtin_amdgcn_s_barrier();

    // ---- p2 ----
    if constexpr (V != 1) {
#pragma unroll
      for (int q = 0; q < 4; ++q) a0[q] = *(const short8*)(buf + arow[q] + s8v[1]);
#pragma unroll
      for (int n = 0; n < 4; ++n) bb[n] = *(const short8*)(buf + brow[n] + s8v[1]);
    }
    if constexpr (V != 3) { if (kt < 35) { stageB(kt + 1, 2, nbuf); stageB(kt + 1, 3, nbuf); } }
    __builtin_amdgcn_s_barrier();
    __builtin_amdgcn_s_setprio(1);
    if constexpr (V != 2) {
#pragma unroll
      for (int q = 0; q < 4; ++q)
#pragma unroll
        for (int n = 0; n < 4; ++n)
          acc[q][n] = __builtin_amdgcn_mfma_f32_16x16x32_bf16(a0[q], bb[n], acc[q][n], 0, 0, 0);
    } else {
#pragma unroll
      for (int q = 0; q < 4; ++q) sink8(a0[q]);
#pragma unroll
      for (int n = 0; n < 4; ++n) sink8(bb[n]);
    }
    __builtin_amdgcn_s_setprio(0);
    asm volatile("s_waitcnt lgkmcnt(0)" ::: "memory");
    __builtin_amdgcn_s_barrier();

    // ---- p3 ----
    if constexpr (V != 1) {
#pragma unroll
      for (int q = 0; q < 4; ++q) a1[q] = *(const short8*)(buf + arow[4 + q] + s8v[1]);
    }
    if constexpr (V != 3) { if (kt < 34) { stageB(kt + 2, 0, buf); stageB(kt + 2, 1, buf); } }
    __builtin_amdgcn_s_barrier();
    __builtin_amdgcn_s_setprio(1);
    if constexpr (V != 2) {
#pragma unroll
      for (int q = 0; q < 4; ++q)
#pragma unroll
        for (int n = 0; n < 4; ++n)
          acc[4 + q][n] = __builtin_amdgcn_mfma_f32_16x16x32_bf16(a1[q], bb[n], acc[4 + q][n], 0, 0, 0);
    } else {
#pragma unroll
      for (int q = 0; q < 4; ++q) sink8(a1[q]);
    }
    __builtin_amdgcn_s_setprio(0);
    asm volatile("s_waitcnt lgkmcnt(0)" ::: "memory");
    if constexpr (V != 3) {
      if (kt < 34)       asm volatile("s_waitcnt vmcnt(2)" ::: "memory");
      else if (kt == 34) asm volatile("s_waitcnt vmcnt(0)" ::: "memory");
    }
    __builtin_amdgcn_s_barrier();
  }

  if constexpr (V == 0) {
    const int rb = (lane >> 4) * 4;
    const int colp = lane & 15;
#pragma unroll
    for (int a = 0; a < 8; ++a) {
      const int co = wm * 128 + (a >> 2) * 64 + (a & 3) * 16 + rb;
      float bv[4];
#pragma unroll
      for (int j = 0; j < 4; ++j) bv[j] = bias[co + j];
#pragma unroll
      for (int n = 0; n < 4; ++n) {
        const int px = wn * 64 + n * 16 + colp;
        const int prow = px >> 6, ow = px & 63;
        const int oh = oh0 + prow;
        if (ow < 62 && oh < 62) {
#pragma unroll
          for (int j = 0; j < 4; ++j)
            out[((size_t)(b * 256 + co + j) * 62 + oh) * 62 + ow] = acc[a][n][j] + bv[j];
        }
      }
    }
  } else if constexpr (V != 2) {
#pragma unroll
    for (int a = 0; a < 8; ++a)
#pragma unroll
      for (int n = 0; n < 4; ++n) sinkf(acc[a][n]);
  }
}

// ---------------------------------------------------------------------------
// Fallback: naive fp32 direct conv (used only if d_ws is too small)
// ---------------------------------------------------------------------------
__global__ __launch_bounds__(256) void conv_naive(const float* __restrict__ x,
                                                  const float* __restrict__ wgt,
                                                  const float* __restrict__ bias,
                                                  float* __restrict__ out) {
  const size_t idx = (size_t)blockIdx.x * 256 + threadIdx.x;
  if (idx >= (size_t)16 * 256 * 62 * 62) return;
  const int ow = (int)(idx % 62);
  size_t r = idx / 62;
  const int oh = (int)(r % 62); r /= 62;
  const int co = (int)(r % 256);
  const int b = (int)(r / 256);
  float s = bias[co];
  for (int ci = 0; ci < 256; ++ci) {
    const float* xp = x + ((size_t)(b * 256 + ci) * 64 + oh) * 64 + ow;
    const float* wp = wgt + (size_t)(co * 256 + ci) * 9;
#pragma unroll
    for (int kh = 0; kh < 3; ++kh)
#pragma unroll
      for (int kw = 0; kw < 3; ++kw)
        s += xp[kh * 64 + kw] * wp[kh * 3 + kw];
  }
  out[idx] = s;
}

extern "C" void kernel_launch(void* const* d_in, const int* in_sizes, int n_in,
                              void* d_out, int out_size, void* d_ws, size_t ws_size,
                              hipStream_t stream) {
  const float* x = (const float*)d_in[0];
  const float* wgt = (const float*)d_in[1];
  const float* bias = (const float*)d_in[2];
  float* out = (float*)d_out;

  const size_t xt_elems = (size_t)16 * 64 * 64 * 256;
  const size_t wr_elems = (size_t)9 * 256 * 256;
  const size_t need = (xt_elems + wr_elems) * sizeof(unsigned short);

  if (ws_size < need) {
    conv_naive<<<61504, 256, 0, stream>>>(x, wgt, bias, out);
    return;
  }

  unsigned short* xt = (unsigned short*)d_ws;
  unsigned short* wrp = xt + xt_elems;

  xpose_kernel<<<4096, 256, 0, stream>>>(x, xt);
  wpack_kernel<<<2304, 256, 0, stream>>>(wgt, wrp);
  // Ablation dispatches (diagnostic; no output writes):
  conv_8ph<1><<<256, 512, 0, stream>>>(xt, wrp, bias, out);  // no ds_read
  conv_8ph<2><<<256, 512, 0, stream>>>(xt, wrp, bias, out);  // no MFMA
  conv_8ph<3><<<256, 512, 0, stream>>>(xt, wrp, bias, out);  // no staging
  // Real kernel (writes out):
  conv_8ph<0><<<256, 512, 0, stream>>>(xt, wrp, bias, out);
}

// Round 10
// 109.226 us; speedup vs baseline: 2.1264x; 2.1264x over previous
//
#include <hip/hip_runtime.h>
#include <stdint.h>

typedef short short8 __attribute__((ext_vector_type(8)));
typedef float f32x4 __attribute__((ext_vector_type(4)));

#define AS1 __attribute__((address_space(1)))
#define AS3 __attribute__((address_space(3)))

__device__ __forceinline__ void gl_lds16(const void* g, void* l) {
  __builtin_amdgcn_global_load_lds((const AS1 unsigned int*)g,
                                   (AS3 unsigned int*)l, 16, 0, 0);
}

__device__ __forceinline__ unsigned short f2bf(float f) {
  union { float f; unsigned int u; } v; v.f = f;
  return (unsigned short)((v.u + (((v.u >> 16) & 1u) + 0x7fffu)) >> 16);
}

// ---------------------------------------------------------------------------
// Pre-pass 1: x [16][256][64][64] fp32 NCHW -> x_t [16][64][64][256] bf16 NHWC
// ---------------------------------------------------------------------------
__global__ __launch_bounds__(256) void xpose_kernel(const float* __restrict__ x,
                                                    unsigned short* __restrict__ xt) {
  __shared__ float tile[64][68];
  const int bid = blockIdx.x;
  const int cchunk = bid & 3;
  const int y = (bid >> 2) & 63;
  const int b = bid >> 8;
  const int t = threadIdx.x;
  const int ci0 = cchunk * 64;

  const int cc = t >> 2;
  const int xo = (t & 3) * 16;
  const float* src = x + (((size_t)(b * 256 + ci0 + cc) * 64 + y) * 64 + xo);
  float4 v0 = ((const float4*)src)[0];
  float4 v1 = ((const float4*)src)[1];
  float4 v2 = ((const float4*)src)[2];
  float4 v3 = ((const float4*)src)[3];
  *(float4*)&tile[cc][xo + 0]  = v0;
  *(float4*)&tile[cc][xo + 4]  = v1;
  *(float4*)&tile[cc][xo + 8]  = v2;
  *(float4*)&tile[cc][xo + 12] = v3;
  __syncthreads();

  const int xpos = t >> 2;
  const int ccg = (t & 3) * 16;
  unsigned int pk[8];
#pragma unroll
  for (int e = 0; e < 8; ++e) {
    unsigned int lo = f2bf(tile[ccg + 2 * e][xpos]);
    unsigned int hi = f2bf(tile[ccg + 2 * e + 1][xpos]);
    pk[e] = lo | (hi << 16);
  }
  unsigned short* dst = xt + ((size_t)(b * 4096 + y * 64 + xpos) * 256 + ci0 + ccg);
  uint4 w0; w0.x = pk[0]; w0.y = pk[1]; w0.z = pk[2]; w0.w = pk[3];
  uint4 w1; w1.x = pk[4]; w1.y = pk[5]; w1.z = pk[6]; w1.w = pk[7];
  ((uint4*)dst)[0] = w0;
  ((uint4*)dst)[1] = w1;
}

// ---------------------------------------------------------------------------
// Pre-pass 2: w [256co][256ci][3][3] fp32 -> w_r [9 tap][256co][256ci] bf16
// ---------------------------------------------------------------------------
__global__ __launch_bounds__(256) void wpack_kernel(const float* __restrict__ w,
                                                    unsigned short* __restrict__ wrp) {
  const int idx = blockIdx.x * 256 + threadIdx.x;
  const int ci = idx & 255;
  const int co = (idx >> 8) & 255;
  const int p = idx >> 16;
  wrp[idx] = f2bf(w[(size_t)(co * 256 + ci) * 9 + p]);
}

// ---------------------------------------------------------------------------
// Main: decoupled implicit-GEMM conv.
// Tile 256co x 256px, 512 thr / 8 waves (wm 2 x wn 4), wave = 128co x 64px.
// B (pixels) -> REGISTERS direct from global (16 cachelines/frag, L2-served,
//   double-buffered sets, no LDS, no barriers).
// A (weights) -> LDS ring-3 (3 x 32 KB), staged 2 K-tiles ahead.
// Sync: ONE s_barrier + ONE counted vmcnt(12) per K-tile (group ledger:
//   12 VMEM/wave/K-tile, groups separated by the memory-clobber asm).
// No explicit lgkm: compiler emits fine-grained per-fragment waits (m97).
// ---------------------------------------------------------------------------
__global__ __launch_bounds__(512, 2) void conv_breg(
    const unsigned short* __restrict__ xt,
    const unsigned short* __restrict__ wrp,
    const float* __restrict__ bias,
    float* __restrict__ out) {
  __shared__ unsigned short lds[3 * 16384];  // A ring: 3 slots x 32 KB

  const int tid = threadIdx.x;
  const int lane = tid & 63;
  const int wv = tid >> 6;
  const int wm = wv >> 2;     // co half (128)
  const int wn = wv & 3;      // px quarter (64)
  const int bid = blockIdx.x;
  const int tile = (bid & 7) * 32 + (bid >> 3);  // bijective XCD swizzle (256%8==0)
  const int b = tile >> 4;
  const int oh0 = (tile & 15) * 4;

  // ---- A staging statics (linear LDS dest, inverse-swizzled global src) ----
  const int crow = tid >> 3;            // 0..63 row within 64-row chunk
  const int cslot = tid & 7;            // 16B slot
  const int sw = cslot ^ (crow & 7);
  const unsigned short* gAbase = wrp + (size_t)crow * 256 + sw * 8;
  const unsigned dstA = crow * 64 + cslot * 8;   // + c*4096, elems in slot

  // ---- fragment statics ----
  const int l15 = lane & 15;
  const int kq = lane >> 4;                      // 0..3 (k-slot)
  const int s8k0 = ((kq) ^ (lane & 7)) * 8;      // swizzled A k0 slice
  const int s8k1 = ((kq + 4) ^ (lane & 7)) * 8;  // swizzled A k1 slice

  // per-lane B pointers: row = px, k-slot folded in; OOB px clamped (discarded
  // in epilogue); y+kh<=63, xc+kw<=63 stay in-bounds.
  const unsigned short* pB[4];
#pragma unroll
  for (int n = 0; n < 4; ++n) {
    const int px = wn * 64 + n * 16 + l15;
    const int y = min(oh0 + (px >> 6), 61);
    const int xc = min(px & 63, 61);
    pB[n] = xt + ((size_t)(b * 64 + y) * 64 + xc) * 256 + kq * 8;
  }

  auto stageA = [&](int kt2, unsigned short* pst) {
    const int tap = kt2 >> 2, ci0 = (kt2 & 3) * 64;
    const unsigned short* g = gAbase + tap * 65536 + ci0;
#pragma unroll
    for (int c = 0; c < 4; ++c)
      gl_lds16(g + c * 16384, pst + c * 4096 + dstA);
  };
  auto loadB = [&](int kt2, short8 (&dst)[4][2]) {
    const int tap = kt2 >> 2, ci0 = (kt2 & 3) * 64;
    const int kh = (tap * 11) >> 5, kw = tap - kh * 3;
    const int boff = (kh * 64 + kw) * 256 + ci0;
#pragma unroll
    for (int n = 0; n < 4; ++n) {
      dst[n][0] = *(const short8*)(pB[n] + boff);
      dst[n][1] = *(const short8*)(pB[n] + boff + 32);
    }
  };

  f32x4 acc[8][4] = {};

  auto ktile = [&](int kt, short8 (&bc)[4][2], unsigned short* pcur,
                   unsigned short* pst) {
    short8 af[4];
    // half 0, k0
#pragma unroll
    for (int q = 0; q < 4; ++q)
      af[q] = *(const short8*)(pcur + (wm * 128 + q * 16 + l15) * 64 + s8k0);
#pragma unroll
    for (int q = 0; q < 4; ++q)
#pragma unroll
      for (int n = 0; n < 4; ++n)
        acc[q][n] = __builtin_amdgcn_mfma_f32_16x16x32_bf16(af[q], bc[n][0], acc[q][n], 0, 0, 0);
    // half 1, k0
#pragma unroll
    for (int q = 0; q < 4; ++q)
      af[q] = *(const short8*)(pcur + (wm * 128 + 64 + q * 16 + l15) * 64 + s8k0);
#pragma unroll
    for (int q = 0; q < 4; ++q)
#pragma unroll
      for (int n = 0; n < 4; ++n)
        acc[4 + q][n] = __builtin_amdgcn_mfma_f32_16x16x32_bf16(af[q], bc[n][0], acc[4 + q][n], 0, 0, 0);
    // half 0, k1
#pragma unroll
    for (int q = 0; q < 4; ++q)
      af[q] = *(const short8*)(pcur + (wm * 128 + q * 16 + l15) * 64 + s8k1);
#pragma unroll
    for (int q = 0; q < 4; ++q)
#pragma unroll
      for (int n = 0; n < 4; ++n)
        acc[q][n] = __builtin_amdgcn_mfma_f32_16x16x32_bf16(af[q], bc[n][1], acc[q][n], 0, 0, 0);
    // half 1, k1
#pragma unroll
    for (int q = 0; q < 4; ++q)
      af[q] = *(const short8*)(pcur + (wm * 128 + 64 + q * 16 + l15) * 64 + s8k1);
#pragma unroll
    for (int q = 0; q < 4; ++q)
#pragma unroll
      for (int n = 0; n < 4; ++n)
        acc[4 + q][n] = __builtin_amdgcn_mfma_f32_16x16x32_bf16(af[q], bc[n][1], acc[4 + q][n], 0, 0, 0);
    // next-next tile: A -> ring slot (kt+2)%3, B -> the set just consumed
    if (kt < 34) { stageA(kt + 2, pst); loadB(kt + 2, bc); }
    // counted drain: (kt+1)'s group of 12 lands; (kt+2)'s 12 stay in flight
    if (kt < 34)       asm volatile("s_waitcnt vmcnt(12)" ::: "memory");
    else if (kt == 34) asm volatile("s_waitcnt vmcnt(0)" ::: "memory");
    __builtin_amdgcn_s_barrier();
  };

  short8 bb0[4][2], bb1[4][2];
  unsigned short* p0 = lds;
  unsigned short* p1 = lds + 16384;
  unsigned short* p2 = lds + 32768;

  // prologue: group(kt=0) then fence then group(kt=1); drain group 0
  stageA(0, p0); loadB(0, bb0);
  asm volatile("" ::: "memory");      // group boundary for the vmcnt ledger
  stageA(1, p1); loadB(1, bb1);
  asm volatile("s_waitcnt vmcnt(12)" ::: "memory");
  __builtin_amdgcn_s_barrier();

  for (int t = 0; t < 18; ++t) {
    ktile(2 * t, bb0, p0, p2);
    unsigned short* tmp = p0; p0 = p1; p1 = p2; p2 = tmp;
    ktile(2 * t + 1, bb1, p0, p2);
    tmp = p0; p0 = p1; p1 = p2; p2 = tmp;
  }

  // ---- epilogue: D col=lane&15 -> px, row=(lane>>4)*4+j -> co ----
  const int rb = (lane >> 4) * 4;
  const int colp = lane & 15;
#pragma unroll
  for (int a = 0; a < 8; ++a) {
    const int co = wm * 128 + (a >> 2) * 64 + (a & 3) * 16 + rb;
    float bv[4];
#pragma unroll
    for (int j = 0; j < 4; ++j) bv[j] = bias[co + j];
#pragma unroll
    for (int n = 0; n < 4; ++n) {
      const int px = wn * 64 + n * 16 + colp;
      const int prow = px >> 6, ow = px & 63;
      const int oh = oh0 + prow;
      if (ow < 62 && oh < 62) {
#pragma unroll
        for (int j = 0; j < 4; ++j)
          out[((size_t)(b * 256 + co + j) * 62 + oh) * 62 + ow] = acc[a][n][j] + bv[j];
      }
    }
  }
}

// ---------------------------------------------------------------------------
// Fallback: naive fp32 direct conv (used only if d_ws is too small)
// ---------------------------------------------------------------------------
__global__ __launch_bounds__(256) void conv_naive(const float* __restrict__ x,
                                                  const float* __restrict__ wgt,
                                                  const float* __restrict__ bias,
                                                  float* __restrict__ out) {
  const size_t idx = (size_t)blockIdx.x * 256 + threadIdx.x;
  if (idx >= (size_t)16 * 256 * 62 * 62) return;
  const int ow = (int)(idx % 62);
  size_t r = idx / 62;
  const int oh = (int)(r % 62); r /= 62;
  const int co = (int)(r % 256);
  const int b = (int)(r / 256);
  float s = bias[co];
  for (int ci = 0; ci < 256; ++ci) {
    const float* xp = x + ((size_t)(b * 256 + ci) * 64 + oh) * 64 + ow;
    const float* wp = wgt + (size_t)(co * 256 + ci) * 9;
#pragma unroll
    for (int kh = 0; kh < 3; ++kh)
#pragma unroll
      for (int kw = 0; kw < 3; ++kw)
        s += xp[kh * 64 + kw] * wp[kh * 3 + kw];
  }
  out[idx] = s;
}

extern "C" void kernel_launch(void* const* d_in, const int* in_sizes, int n_in,
                              void* d_out, int out_size, void* d_ws, size_t ws_size,
                              hipStream_t stream) {
  const float* x = (const float*)d_in[0];
  const float* wgt = (const float*)d_in[1];
  const float* bias = (const float*)d_in[2];
  float* out = (float*)d_out;

  const size_t xt_elems = (size_t)16 * 64 * 64 * 256;
  const size_t wr_elems = (size_t)9 * 256 * 256;
  const size_t need = (xt_elems + wr_elems) * sizeof(unsigned short);

  if (ws_size < need) {
    conv_naive<<<61504, 256, 0, stream>>>(x, wgt, bias, out);
    return;
  }

  unsigned short* xt = (unsigned short*)d_ws;
  unsigned short* wrp = xt + xt_elems;

  xpose_kernel<<<4096, 256, 0, stream>>>(x, xt);
  wpack_kernel<<<2304, 256, 0, stream>>>(wgt, wrp);
  conv_breg<<<256, 512, 0, stream>>>(xt, wrp, bias, out);
}

// Round 12
// 104.747 us; speedup vs baseline: 2.2173x; 1.0428x over previous
//
#include <hip/hip_runtime.h>
#include <stdint.h>

typedef short short8 __attribute__((ext_vector_type(8)));
typedef float f32x4 __attribute__((ext_vector_type(4)));

#define AS1 __attribute__((address_space(1)))
#define AS3 __attribute__((address_space(3)))

__device__ __forceinline__ void gl_lds16(const void* g, void* l) {
  __builtin_amdgcn_global_load_lds((const AS1 unsigned int*)g,
                                   (AS3 unsigned int*)l, 16, 0, 0);
}

__device__ __forceinline__ unsigned short f2bf(float f) {
  union { float f; unsigned int u; } v; v.f = f;
  return (unsigned short)((v.u + (((v.u >> 16) & 1u) + 0x7fffu)) >> 16);
}

// ---------------------------------------------------------------------------
// Pre-pass 1: x [16][256][64][64] fp32 NCHW -> x_t [16][64][64][256] bf16 NHWC
// ---------------------------------------------------------------------------
__global__ __launch_bounds__(256) void xpose_kernel(const float* __restrict__ x,
                                                    unsigned short* __restrict__ xt) {
  __shared__ float tile[64][68];
  const int bid = blockIdx.x;
  const int cchunk = bid & 3;
  const int y = (bid >> 2) & 63;
  const int b = bid >> 8;
  const int t = threadIdx.x;
  const int ci0 = cchunk * 64;

  const int cc = t >> 2;
  const int xo = (t & 3) * 16;
  const float* src = x + (((size_t)(b * 256 + ci0 + cc) * 64 + y) * 64 + xo);
  float4 v0 = ((const float4*)src)[0];
  float4 v1 = ((const float4*)src)[1];
  float4 v2 = ((const float4*)src)[2];
  float4 v3 = ((const float4*)src)[3];
  *(float4*)&tile[cc][xo + 0]  = v0;
  *(float4*)&tile[cc][xo + 4]  = v1;
  *(float4*)&tile[cc][xo + 8]  = v2;
  *(float4*)&tile[cc][xo + 12] = v3;
  __syncthreads();

  const int xpos = t >> 2;
  const int ccg = (t & 3) * 16;
  unsigned int pk[8];
#pragma unroll
  for (int e = 0; e < 8; ++e) {
    unsigned int lo = f2bf(tile[ccg + 2 * e][xpos]);
    unsigned int hi = f2bf(tile[ccg + 2 * e + 1][xpos]);
    pk[e] = lo | (hi << 16);
  }
  unsigned short* dst = xt + ((size_t)(b * 4096 + y * 64 + xpos) * 256 + ci0 + ccg);
  uint4 w0; w0.x = pk[0]; w0.y = pk[1]; w0.z = pk[2]; w0.w = pk[3];
  uint4 w1; w1.x = pk[4]; w1.y = pk[5]; w1.z = pk[6]; w1.w = pk[7];
  ((uint4*)dst)[0] = w0;
  ((uint4*)dst)[1] = w1;
}

// ---------------------------------------------------------------------------
// Pre-pass 2: w [256co][256ci][3][3] fp32 -> w_r [9 tap][256co][256ci] bf16
// ---------------------------------------------------------------------------
__global__ __launch_bounds__(256) void wpack_kernel(const float* __restrict__ w,
                                                    unsigned short* __restrict__ wrp) {
  const int idx = blockIdx.x * 256 + threadIdx.x;
  const int ci = idx & 255;
  const int co = (idx >> 8) & 255;
  const int p = idx >> 16;
  wrp[idx] = f2bf(w[(size_t)(co * 256 + ci) * 9 + p]);
}

// ---------------------------------------------------------------------------
// Main: deep-lookahead ring-4 implicit-GEMM conv.
// Tile 256co x 256px, 512 thr / 8 waves (wm 2 x wn 4), wave = 128co x 64px.
// 72 K-tiles of BK=32, ring-4 x 32KB LDS slots, stage kt+2 during kt
// (2-4 phases of load slack, m201-depth), ONE counted vmcnt(4)/K-tile.
// 2 phases per K-tile: p0 {8 ds_read | stage A(kt+2) | bar | 16 MFMA},
//                      p1 {4 ds_read | stage B(kt+2) | bar | 16 MFMA}.
// T2 swizzle slot = (lane>>4) ^ (row&3), T5 setprio.
// ---------------------------------------------------------------------------
__global__ __launch_bounds__(512, 2) void conv_ring4(
    const unsigned short* __restrict__ xt,
    const unsigned short* __restrict__ wrp,
    const float* __restrict__ bias,
    float* __restrict__ out) {
  __shared__ unsigned short lds[4][16384];  // slot: A [0,8192) 256co x 32k, B [8192,16384) 256px x 32k

  const int tid = threadIdx.x;
  const int lane = tid & 63;
  const int wv = tid >> 6;
  const int wm = wv >> 2;     // co half (128)
  const int wn = wv & 3;      // px quarter (64)
  const int bid = blockIdx.x;
  const int tile = (bid & 7) * 32 + (bid >> 3);  // bijective XCD swizzle (256%8==0)
  const int b = tile >> 4;
  const int oh0 = (tile & 15) * 4;

  // ---- staging statics: thread t covers rows {srow, srow+128}, 16B slot slin ----
  const int srow = tid >> 2;            // 0..127
  const int slin = tid & 3;
  const int sw = slin ^ (srow & 3);     // inverse-swizzled global slot (row&3 invariant under +128)
  const unsigned short* gA = wrp + (size_t)srow * 256 + sw * 8;
  const unsigned short* gB[2];
#pragma unroll
  for (int i = 0; i < 2; ++i) {
    const int px = i * 128 + srow;
    const int y = min(oh0 + (px >> 6), 61);   // clamp pad rows (y+kh<=63)
    const int xc = min(px & 63, 61);          // clamp pad cols (xc+kw<=63)
    gB[i] = xt + ((size_t)(b * 64 + y) * 64 + xc) * 256 + sw * 8;
  }
  const unsigned dstA = srow * 32 + slin * 8;  // + i*4096 ; B: +8192

  auto stageA = [&](int kt2) {
    const int tap = kt2 >> 3, ci0 = (kt2 & 7) * 32;
    unsigned short* s = &lds[kt2 & 3][0];
    const unsigned short* g = gA + tap * 65536 + ci0;
    gl_lds16(g, s + dstA);
    gl_lds16(g + 128 * 256, s + 4096 + dstA);
  };
  auto stageB = [&](int kt2) {
    const int tap = kt2 >> 3, ci0 = (kt2 & 7) * 32;
    const int kh = (tap * 11) >> 5, kw = tap - kh * 3;
    const int off = (kh * 64 + kw) * 256 + ci0;
    unsigned short* s = &lds[kt2 & 3][0];
    gl_lds16(gB[0] + off, s + 8192 + dstA);
    gl_lds16(gB[1] + off, s + 8192 + 4096 + dstA);
  };

  // ---- fragment statics: slot = (lane>>4) ^ (l15&3) (balanced quads, 0-conflict) ----
  const int l15 = lane & 15;
  const int fsl = (((lane >> 4)) ^ (l15 & 3)) * 8;

  f32x4 acc[8][4] = {};

  // prologue: fill slots 0,1 (8 loads); drain slot 0; slot 1 stays in flight
  stageA(0); stageB(0);
  stageA(1); stageB(1);
  asm volatile("s_waitcnt vmcnt(4)" ::: "memory");
  __builtin_amdgcn_s_barrier();

  for (int kt = 0; kt < 72; ++kt) {
    const unsigned short* s = &lds[kt & 3][0];
    short8 af[4], bf[4];

    // ---- p0: A frags m0-3 + B frags; stage A(kt+2) ----
#pragma unroll
    for (int m = 0; m < 4; ++m)
      af[m] = *(const short8*)(s + (wm * 128 + m * 16 + l15) * 32 + fsl);
#pragma unroll
    for (int n = 0; n < 4; ++n)
      bf[n] = *(const short8*)(s + 8192 + (wn * 64 + n * 16 + l15) * 32 + fsl);
    if (kt < 70) stageA(kt + 2);
    __builtin_amdgcn_s_barrier();
    __builtin_amdgcn_s_setprio(1);
#pragma unroll
    for (int m = 0; m < 4; ++m)
#pragma unroll
      for (int n = 0; n < 4; ++n)
        acc[m][n] = __builtin_amdgcn_mfma_f32_16x16x32_bf16(af[m], bf[n], acc[m][n], 0, 0, 0);
    __builtin_amdgcn_s_setprio(0);
    asm volatile("s_waitcnt lgkmcnt(0)" ::: "memory");
    __builtin_amdgcn_s_barrier();

    // ---- p1: A frags m4-7, reuse B regs; stage B(kt+2) ----
#pragma unroll
    for (int m = 0; m < 4; ++m)
      af[m] = *(const short8*)(s + (wm * 128 + (4 + m) * 16 + l15) * 32 + fsl);
    if (kt < 70) stageB(kt + 2);
    __builtin_amdgcn_s_barrier();
    __builtin_amdgcn_s_setprio(1);
#pragma unroll
    for (int m = 0; m < 4; ++m)
#pragma unroll
      for (int n = 0; n < 4; ++n)
        acc[4 + m][n] = __builtin_amdgcn_mfma_f32_16x16x32_bf16(af[m], bf[n], acc[4 + m][n], 0, 0, 0);
    __builtin_amdgcn_s_setprio(0);
    asm volatile("s_waitcnt lgkmcnt(0)" ::: "memory");
    // counted drain once per K-tile: kt+1's 4 loads landed; kt+2's 4 in flight
    if (kt <= 69)      asm volatile("s_waitcnt vmcnt(4)" ::: "memory");
    else if (kt == 70) asm volatile("s_waitcnt vmcnt(0)" ::: "memory");
    __builtin_amdgcn_s_barrier();
  }

  // ---- epilogue: D col=lane&15 -> px, row=(lane>>4)*4+j -> co ----
  const int rb = (lane >> 4) * 4;
  const int colp = lane & 15;
#pragma unroll
  for (int m = 0; m < 8; ++m) {
    const int co = wm * 128 + m * 16 + rb;
    float bv[4];
#pragma unroll
    for (int j = 0; j < 4; ++j) bv[j] = bias[co + j];
#pragma unroll
    for (int n = 0; n < 4; ++n) {
      const int px = wn * 64 + n * 16 + colp;
      const int prow = px >> 6, ow = px & 63;
      const int oh = oh0 + prow;
      if (ow < 62 && oh < 62) {
#pragma unroll
        for (int j = 0; j < 4; ++j)
          out[((size_t)(b * 256 + co + j) * 62 + oh) * 62 + ow] = acc[m][n][j] + bv[j];
      }
    }
  }
}

// ---------------------------------------------------------------------------
// Fallback: naive fp32 direct conv (used only if d_ws is too small)
// ---------------------------------------------------------------------------
__global__ __launch_bounds__(256) void conv_naive(const float* __restrict__ x,
                                                  const float* __restrict__ wgt,
                                                  const float* __restrict__ bias,
                                                  float* __restrict__ out) {
  const size_t idx = (size_t)blockIdx.x * 256 + threadIdx.x;
  if (idx >= (size_t)16 * 256 * 62 * 62) return;
  const int ow = (int)(idx % 62);
  size_t r = idx / 62;
  const int oh = (int)(r % 62); r /= 62;
  const int co = (int)(r % 256);
  const int b = (int)(r / 256);
  float s = bias[co];
  for (int ci = 0; ci < 256; ++ci) {
    const float* xp = x + ((size_t)(b * 256 + ci) * 64 + oh) * 64 + ow;
    const float* wp = wgt + (size_t)(co * 256 + ci) * 9;
#pragma unroll
    for (int kh = 0; kh < 3; ++kh)
#pragma unroll
      for (int kw = 0; kw < 3; ++kw)
        s += xp[kh * 64 + kw] * wp[kh * 3 + kw];
  }
  out[idx] = s;
}

extern "C" void kernel_launch(void* const* d_in, const int* in_sizes, int n_in,
                              void* d_out, int out_size, void* d_ws, size_t ws_size,
                              hipStream_t stream) {
  const float* x = (const float*)d_in[0];
  const float* wgt = (const float*)d_in[1];
  const float* bias = (const float*)d_in[2];
  float* out = (float*)d_out;

  const size_t xt_elems = (size_t)16 * 64 * 64 * 256;
  const size_t wr_elems = (size_t)9 * 256 * 256;
  const size_t need = (xt_elems + wr_elems) * sizeof(unsigned short);

  if (ws_size < need) {
    conv_naive<<<61504, 256, 0, stream>>>(x, wgt, bias, out);
    return;
  }

  unsigned short* xt = (unsigned short*)d_ws;
  unsigned short* wrp = xt + xt_elems;

  xpose_kernel<<<4096, 256, 0, stream>>>(x, xt);
  wpack_kernel<<<2304, 256, 0, stream>>>(wgt, wrp);
  conv_ring4<<<256, 512, 0, stream>>>(xt, wrp, bias, out);
}

// Round 13
// 89.074 us; speedup vs baseline: 2.6075x; 1.1760x over previous
//
#include <hip/hip_runtime.h>
#include <stdint.h>

typedef short short8 __attribute__((ext_vector_type(8)));
typedef float f32x4 __attribute__((ext_vector_type(4)));

#define AS1 __attribute__((address_space(1)))
#define AS3 __attribute__((address_space(3)))

__device__ __forceinline__ void gl_lds16(const void* g, void* l) {
  __builtin_amdgcn_global_load_lds((const AS1 unsigned int*)g,
                                   (AS3 unsigned int*)l, 16, 0, 0);
}

__device__ __forceinline__ unsigned short f2bf(float f) {
  union { float f; unsigned int u; } v; v.f = f;
  return (unsigned short)((v.u + (((v.u >> 16) & 1u) + 0x7fffu)) >> 16);
}

// ---------------------------------------------------------------------------
// Pre-pass 1: x [16][256][64][64] fp32 NCHW -> x_t [16][64][64][256] bf16 NHWC
// ---------------------------------------------------------------------------
__global__ __launch_bounds__(256) void xpose_kernel(const float* __restrict__ x,
                                                    unsigned short* __restrict__ xt) {
  __shared__ float tile[64][68];
  const int bid = blockIdx.x;
  const int cchunk = bid & 3;
  const int y = (bid >> 2) & 63;
  const int b = bid >> 8;
  const int t = threadIdx.x;
  const int ci0 = cchunk * 64;

  const int cc = t >> 2;
  const int xo = (t & 3) * 16;
  const float* src = x + (((size_t)(b * 256 + ci0 + cc) * 64 + y) * 64 + xo);
  float4 v0 = ((const float4*)src)[0];
  float4 v1 = ((const float4*)src)[1];
  float4 v2 = ((const float4*)src)[2];
  float4 v3 = ((const float4*)src)[3];
  *(float4*)&tile[cc][xo + 0]  = v0;
  *(float4*)&tile[cc][xo + 4]  = v1;
  *(float4*)&tile[cc][xo + 8]  = v2;
  *(float4*)&tile[cc][xo + 12] = v3;
  __syncthreads();

  const int xpos = t >> 2;
  const int ccg = (t & 3) * 16;
  unsigned int pk[8];
#pragma unroll
  for (int e = 0; e < 8; ++e) {
    unsigned int lo = f2bf(tile[ccg + 2 * e][xpos]);
    unsigned int hi = f2bf(tile[ccg + 2 * e + 1][xpos]);
    pk[e] = lo | (hi << 16);
  }
  unsigned short* dst = xt + ((size_t)(b * 4096 + y * 64 + xpos) * 256 + ci0 + ccg);
  uint4 w0; w0.x = pk[0]; w0.y = pk[1]; w0.z = pk[2]; w0.w = pk[3];
  uint4 w1; w1.x = pk[4]; w1.y = pk[5]; w1.z = pk[6]; w1.w = pk[7];
  ((uint4*)dst)[0] = w0;
  ((uint4*)dst)[1] = w1;
}

// ---------------------------------------------------------------------------
// Pre-pass 2: w [256co][256ci][3][3] fp32 -> w_r [9 tap][256co][256ci] bf16
// ---------------------------------------------------------------------------
__global__ __launch_bounds__(256) void wpack_kernel(const float* __restrict__ w,
                                                    unsigned short* __restrict__ wrp) {
  const int idx = blockIdx.x * 256 + threadIdx.x;
  const int ci = idx & 255;
  const int co = (idx >> 8) & 255;
  const int p = idx >> 16;
  wrp[idx] = f2bf(w[(size_t)(co * 256 + ci) * 9 + p]);
}

// ---------------------------------------------------------------------------
// Main: barrier-light software-pipelined implicit-GEMM conv.
// R7's exact geometry (256co x 256px, 8 waves 2x4, BK=64, dbuf 2x64KB,
// proven 0-conflict XOR swizzle) but NEW sync structure:
//   - 4 phases per K-tile, NO barriers between phases
//   - each phase ISSUES the next phase's ds_reads (sched_barrier(0) pins
//     issue-ahead), then MFMAs on regs loaded last phase; compiler inserts
//     counted lgkm waits for its own loads -> LDS port drains next phase's
//     reads DURING this phase's MFMA
//   - ONE {vmcnt(0); lgkm(0); barrier} per K-tile at p3 (race-free: every
//     wave's buffer reads drain before the barrier; stages follow it)
// Barriers: 288 -> 36.
// ---------------------------------------------------------------------------
__global__ __launch_bounds__(512, 2) void conv_pipe(
    const unsigned short* __restrict__ xt,
    const unsigned short* __restrict__ wrp,
    const float* __restrict__ bias,
    float* __restrict__ out) {
  __shared__ unsigned short lds[2][32768];  // per buf: A [0,16384), B [16384,32768) elems

  const int tid = threadIdx.x;
  const int lane = tid & 63;
  const int wv = tid >> 6;
  const int wm = wv >> 2;     // co half (128)
  const int wn = wv & 3;      // px quarter (64)
  const int bid = blockIdx.x;
  const int tile = (bid & 7) * 32 + (bid >> 3);  // bijective XCD swizzle (256%8==0)
  const int b = tile >> 4;
  const int oh0 = (tile & 15) * 4;

  // ---- staging statics (R7 verbatim): chunk = 64 rows x k64 = 8KB ----
  const int crow = tid >> 3;            // 0..63
  const int cslot = tid & 7;            // 16B slot
  const int sw = cslot ^ (crow & 7);    // inverse-swizzled source slot
  const unsigned short* gAbase = wrp + (size_t)crow * 256 + sw * 8;
  const unsigned short* gBbase[4];
#pragma unroll
  for (int cb = 0; cb < 4; ++cb) {
    const int y = min(oh0 + cb, 61);
    const int x = min(crow, 61);
    gBbase[cb] = xt + ((size_t)(b * 64 + y) * 64 + x) * 256 + sw * 8;
  }
  const unsigned dst_rc = crow * 64 + cslot * 8;

  // ---- fragment statics (R7 verbatim, measured 0-conflict) ----
  const int l15 = lane & 15;
  int s8v[2];
  s8v[0] = (((lane >> 4)) ^ (lane & 7)) * 8;
  s8v[1] = (((lane >> 4) + 4) ^ (lane & 7)) * 8;
  int arow[8], brow[4];
#pragma unroll
  for (int a = 0; a < 8; ++a)
    arow[a] = (wm * 128 + (a >> 2) * 64 + (a & 3) * 16 + l15) * 64;
#pragma unroll
  for (int n = 0; n < 4; ++n)
    brow[n] = 16384 + (wn * 64 + n * 16 + l15) * 64;

  auto stageA = [&](int kt2, unsigned short* bufp) {
    const int tap = kt2 >> 2, ci0 = (kt2 & 3) * 64;
    const unsigned short* g = gAbase + tap * 65536 + ci0;
#pragma unroll
    for (int c = 0; c < 4; ++c)
      gl_lds16(g + c * 16384, bufp + c * 4096 + dst_rc);
  };
  auto stageB = [&](int kt2, unsigned short* bufp) {
    const int tap = kt2 >> 2, ci0 = (kt2 & 3) * 64;
    const int kh = (tap * 11) >> 5, kw = tap - kh * 3;
    const int off = (kh * 64 + kw) * 256 + ci0;
#pragma unroll
    for (int cb = 0; cb < 4; ++cb)
      gl_lds16(gBbase[cb] + off, bufp + (4 + cb) * 4096 + dst_rc);
  };

  f32x4 acc[8][4] = {};
  unsigned short* buf0 = &lds[0][0];
  unsigned short* buf1 = &lds[1][0];

  // prologue: stage K-tile 0 fully; drain; load p0 fragments
  stageA(0, buf0);
  stageB(0, buf0);
  asm volatile("s_waitcnt vmcnt(0)" ::: "memory");
  __builtin_amdgcn_s_barrier();

  short8 a_cur[4], b_cur[4], a_nxt[4], b_nxt[4];
#pragma unroll
  for (int q = 0; q < 4; ++q) a_cur[q] = *(const short8*)(buf0 + arow[q] + s8v[0]);
#pragma unroll
  for (int n = 0; n < 4; ++n) b_cur[n] = *(const short8*)(buf0 + brow[n] + s8v[0]);

  for (int kt = 0; kt < 36; ++kt) {
    const unsigned short* buf = (kt & 1) ? buf1 : buf0;
    unsigned short* nbuf = (kt & 1) ? buf0 : buf1;

    // ---- p0: issue p1 frags (A m4-7 k0) + stage A(kt+1); MFMA m0-3 k0 ----
#pragma unroll
    for (int q = 0; q < 4; ++q) a_nxt[q] = *(const short8*)(buf + arow[4 + q] + s8v[0]);
    if (kt < 35) stageA(kt + 1, nbuf);
    __builtin_amdgcn_sched_barrier(0);
    __builtin_amdgcn_s_setprio(1);
#pragma unroll
    for (int q = 0; q < 4; ++q)
#pragma unroll
      for (int n = 0; n < 4; ++n)
        acc[q][n] = __builtin_amdgcn_mfma_f32_16x16x32_bf16(a_cur[q], b_cur[n], acc[q][n], 0, 0, 0);
    __builtin_amdgcn_s_setprio(0);

    // ---- p1: issue p2 frags (A m0-3 k1, B k1) + stage B(kt+1); MFMA m4-7 k0 ----
#pragma unroll
    for (int q = 0; q < 4; ++q) a_cur[q] = *(const short8*)(buf + arow[q] + s8v[1]);
#pragma unroll
    for (int n = 0; n < 4; ++n) b_nxt[n] = *(const short8*)(buf + brow[n] + s8v[1]);
    if (kt < 35) stageB(kt + 1, nbuf);
    __builtin_amdgcn_sched_barrier(0);
    __builtin_amdgcn_s_setprio(1);
#pragma unroll
    for (int q = 0; q < 4; ++q)
#pragma unroll
      for (int n = 0; n < 4; ++n)
        acc[4 + q][n] = __builtin_amdgcn_mfma_f32_16x16x32_bf16(a_nxt[q], b_cur[n], acc[4 + q][n], 0, 0, 0);
    __builtin_amdgcn_s_setprio(0);

    // ---- p2: issue p3 frags (A m4-7 k1); MFMA m0-3 k1 ----
#pragma unroll
    for (int q = 0; q < 4; ++q) a_nxt[q] = *(const short8*)(buf + arow[4 + q] + s8v[1]);
    __builtin_amdgcn_sched_barrier(0);
    __builtin_amdgcn_s_setprio(1);
#pragma unroll
    for (int q = 0; q < 4; ++q)
#pragma unroll
      for (int n = 0; n < 4; ++n)
        acc[q][n] = __builtin_amdgcn_mfma_f32_16x16x32_bf16(a_cur[q], b_nxt[n], acc[q][n], 0, 0, 0);
    __builtin_amdgcn_s_setprio(0);

    // ---- p3: K-tile boundary drain + barrier; issue next p0 frags; MFMA m4-7 k1 ----
    if (kt < 35) {
      asm volatile("s_waitcnt vmcnt(0)" ::: "memory");   // kt+1 stages landed (this wave)
      asm volatile("s_waitcnt lgkmcnt(0)" ::: "memory"); // all my buffer reads done
      __builtin_amdgcn_s_barrier();                      // globally: stages visible, reads drained
#pragma unroll
      for (int q = 0; q < 4; ++q) a_cur[q] = *(const short8*)(nbuf + arow[q] + s8v[0]);
#pragma unroll
      for (int n = 0; n < 4; ++n) b_cur[n] = *(const short8*)(nbuf + brow[n] + s8v[0]);
    }
    __builtin_amdgcn_sched_barrier(0);
    __builtin_amdgcn_s_setprio(1);
#pragma unroll
    for (int q = 0; q < 4; ++q)
#pragma unroll
      for (int n = 0; n < 4; ++n)
        acc[4 + q][n] = __builtin_amdgcn_mfma_f32_16x16x32_bf16(a_nxt[q], b_nxt[n], acc[4 + q][n], 0, 0, 0);
    __builtin_amdgcn_s_setprio(0);
  }

  // ---- epilogue (R7 verbatim): D col=lane&15 -> px, row=(lane>>4)*4+j -> co ----
  const int rb = (lane >> 4) * 4;
  const int colp = lane & 15;
#pragma unroll
  for (int a = 0; a < 8; ++a) {
    const int co = wm * 128 + (a >> 2) * 64 + (a & 3) * 16 + rb;
    float bv[4];
#pragma unroll
    for (int j = 0; j < 4; ++j) bv[j] = bias[co + j];
#pragma unroll
    for (int n = 0; n < 4; ++n) {
      const int px = wn * 64 + n * 16 + colp;
      const int prow = px >> 6, ow = px & 63;
      const int oh = oh0 + prow;
      if (ow < 62 && oh < 62) {
#pragma unroll
        for (int j = 0; j < 4; ++j)
          out[((size_t)(b * 256 + co + j) * 62 + oh) * 62 + ow] = acc[a][n][j] + bv[j];
      }
    }
  }
}

// ---------------------------------------------------------------------------
// Fallback: naive fp32 direct conv (used only if d_ws is too small)
// ---------------------------------------------------------------------------
__global__ __launch_bounds__(256) void conv_naive(const float* __restrict__ x,
                                                  const float* __restrict__ wgt,
                                                  const float* __restrict__ bias,
                                                  float* __restrict__ out) {
  const size_t idx = (size_t)blockIdx.x * 256 + threadIdx.x;
  if (idx >= (size_t)16 * 256 * 62 * 62) return;
  const int ow = (int)(idx % 62);
  size_t r = idx / 62;
  const int oh = (int)(r % 62); r /= 62;
  const int co = (int)(r % 256);
  const int b = (int)(r / 256);
  float s = bias[co];
  for (int ci = 0; ci < 256; ++ci) {
    const float* xp = x + ((size_t)(b * 256 + ci) * 64 + oh) * 64 + ow;
    const float* wp = wgt + (size_t)(co * 256 + ci) * 9;
#pragma unroll
    for (int kh = 0; kh < 3; ++kh)
#pragma unroll
      for (int kw = 0; kw < 3; ++kw)
        s += xp[kh * 64 + kw] * wp[kh * 3 + kw];
  }
  out[idx] = s;
}

extern "C" void kernel_launch(void* const* d_in, const int* in_sizes, int n_in,
                              void* d_out, int out_size, void* d_ws, size_t ws_size,
                              hipStream_t stream) {
  const float* x = (const float*)d_in[0];
  const float* wgt = (const float*)d_in[1];
  const float* bias = (const float*)d_in[2];
  float* out = (float*)d_out;

  const size_t xt_elems = (size_t)16 * 64 * 64 * 256;
  const size_t wr_elems = (size_t)9 * 256 * 256;
  const size_t need = (xt_elems + wr_elems) * sizeof(unsigned short);

  if (ws_size < need) {
    conv_naive<<<61504, 256, 0, stream>>>(x, wgt, bias, out);
    return;
  }

  unsigned short* xt = (unsigned short*)d_ws;
  unsigned short* wrp = xt + xt_elems;

  xpose_kernel<<<4096, 256, 0, stream>>>(x, xt);
  wpack_kernel<<<2304, 256, 0, stream>>>(wgt, wrp);
  conv_pipe<<<256, 512, 0, stream>>>(xt, wrp, bias, out);
}